// Round 10
// baseline (277.241 us; speedup 1.0000x reference)
//
#include <hip/hip_runtime.h>
#include <stdint.h>

// Problem constants (fixed by reference)
#define NB 32    // batch
#define NC 64    // input channels
#define NH 64
#define NW 64
#define NO 512   // output channels
// xh padded layout: [NB][66 hp][66 wp][64 c], hp/wp 0 and 65 are zeros

typedef __bf16 bf16x8 __attribute__((ext_vector_type(8)));
typedef short  s16x8  __attribute__((ext_vector_type(8)));
typedef float  f32x4  __attribute__((ext_vector_type(4)));
typedef float  f32x16 __attribute__((ext_vector_type(16)));

__device__ __forceinline__ uint16_t f2bf(float f) {
  uint32_t u = __builtin_bit_cast(uint32_t, f);
  u += 0x7fffu + ((u >> 16) & 1u);   // round-to-nearest-even
  return (uint16_t)(u >> 16);
}

// async global->LDS, 16B per lane. LDS dest = wave-uniform base + lane*16.
__device__ __forceinline__ void gld16(const uint16_t* g, uint16_t* l) {
  __builtin_amdgcn_global_load_lds(
      (const __attribute__((address_space(1))) void*)(g),
      (__attribute__((address_space(3))) void*)(l), 16, 0, 0);
}

// ---------------- kernel 1: fused prep (build_w + nhwc transpose) --------
// bid < NO: W_eff[o][c][p] = sum_s coef[o,s]*dict[idx[o,s]][c][p] ->
//   Wl[((p*NO + o)*8 + ((c>>3) ^ (o&7)))*8 + (c&7)]   (pre-swizzled)
// bid >= NO: x NCHW fp32 -> xh[b][hp][wp][c] bf16, hp/wp-padded (66x66),
//   16B chunk (c>>3) of col wp stored at chunk slot ((c>>3) ^ (wp&7)).
__global__ void k_prep(const float* __restrict__ dict,
                       const float* __restrict__ coef,
                       const int*   __restrict__ idx,
                       const float* __restrict__ x,
                       uint16_t*    __restrict__ Wl,
                       uint16_t*    __restrict__ xh) {
  const int bid = blockIdx.x;
  const int t = threadIdx.x;            // 256
  if (bid < NO) {                       // ---- build_w for o = bid ----
    __shared__ float tmp[576];
    const int o = bid;
#pragma unroll
    for (int j = 0; j < 3; ++j) {
      const int id = t + j * 256;
      if (id < 576) {
        float v = 0.f;
#pragma unroll
        for (int s = 0; s < 4; ++s)
          v += coef[o * 4 + s] * dict[idx[o * 4 + s] * 576 + id];
        tmp[id] = v;
      }
    }
    __syncthreads();
#pragma unroll
    for (int j = 0; j < 3; ++j) {
      const int id = t + j * 256;
      if (id < 576) {
        const int c = id & 63, p = id >> 6;
        const int sl = ((p * NO + o) * 8 + ((c >> 3) ^ (o & 7))) * 8 + (c & 7);
        Wl[sl] = f2bf(tmp[c * 9 + p]);
      }
    }
    return;
  }
  // ---- nhwc for bh = bid - NO ----
  const int bh = bid - NO;              // b*66 + hp
  const int b = bh / 66, hp = bh % 66;
  uint16_t* row = xh + (size_t)(b * 66 + hp) * 4224;   // 66*64 elems
  int4* r4 = reinterpret_cast<int4*>(row);             // 528 int4
  if (hp == 0 || hp == 65) {            // zero h-pad rows
    for (int j = t; j < 528; j += 256) r4[j] = int4{0, 0, 0, 0};
    return;
  }
  __shared__ float tile[64][65];
  const int h = hp - 1;
  const int w = t & 63;
#pragma unroll
  for (int c = (t >> 6); c < 64; c += 4)
    tile[c][w] = x[((size_t)(b * NC + c) * NH + h) * NW + w];
  __syncthreads();
  if (t < 16)                           // zero w-pad cols wp=0 and wp=65
    r4[(t >> 3) * 520 + (t & 7)] = int4{0, 0, 0, 0};
#pragma unroll
  for (int i = 0; i < 2; ++i) {
    const int s = t + i * 256;          // 512 slots: w2 (0..63), cb (0..7)
    const int w2 = s >> 3, cb = s & 7;
    const int wp = w2 + 1;              // padded col
    uint32_t d[4];
#pragma unroll
    for (int j = 0; j < 4; ++j) {
      const uint32_t lo = f2bf(tile[cb * 8 + 2 * j][w2]);
      const uint32_t hi = f2bf(tile[cb * 8 + 2 * j + 1][w2]);
      d[j] = lo | (hi << 16);
    }
    r4[wp * 8 + (cb ^ (wp & 7))] =
        int4{(int)d[0], (int)d[1], (int)d[2], (int)d[3]};
  }
}

// ---------------- kernel 2: 32x32x16-MFMA implicit-GEMM conv -------------
// 1024 blocks (4 rounds), 512 thr (8 waves). Block = 128 o x 512 pix
// (8 h-rows of one b). Wave = 64 pix (1 h-row) x 128 o:
// acc = 2 pix-sub x 4 o-sub of 32x32, f32x16 each (128 VGPR).
// Per k-step(16): 2 braw + 4 af ds_reads feed 8 MFMAs (43.7K FLOP/read,
// 1.33x the 16x16 scheme -> LDS floor 46->34.6 us).
// xs = 10 fully-padded xh rows, flat-copied once (82.5 KB). as = one
// dw-group (3 taps x 128 o, 48 KB), restaged twice with coarse barriers.
// Total LDS 133,632 B -> 1 block/CU. Only 5 barriers in the kernel.
__global__ __launch_bounds__(512, 2) void k_conv(
    const uint16_t* __restrict__ xh,   // [NB][66][66][64] bf16, pre-swizzled
    const uint16_t* __restrict__ Wl,   // [9][512][64] bf16, pre-swizzled
    const float*    __restrict__ bias,
    float*          __restrict__ out) {
  __shared__ __align__(16) uint16_t xs[10 * 4224];      // 84,480 B
  __shared__ __align__(16) uint16_t as[3 * 128 * 64];   // 49,152 B

  const int t = threadIdx.x;
  const int lane = t & 63;
  const int wid  = t >> 6;      // 0..7
  // XCD-chunked: XCD j gets contiguous s-range (4 b's, L2-resident)
  const int flat = blockIdx.x;                 // 1024 blocks
  const int s    = (flat & 7) * 128 + (flat >> 3);
  const int ot   = s & 3;                      // o-tile (4 x 128)
  const int pt   = s >> 2;                     // pixel tile: b*8 + h-octet
  const int O0 = ot * 128;
  const int b  = pt >> 3;
  const int h0 = (pt & 7) * 8;

  // ---- stage xs: flat copy of xh rows [b][h0 .. h0+10) (84,480 B) ----
  {
    const uint16_t* src = xh + (size_t)(b * 66 + h0) * 4224;
#pragma unroll
    for (int j = 0; j < 10; ++j) {
      const int ch = wid + j * 8;              // 0..79
      gld16(src + ch * 512 + lane * 8, xs + ch * 512);
    }
    if (wid < 2) {                             // chunks 80, 81
      const int ch = 80 + wid;
      gld16(src + ch * 512 + lane * 8, xs + ch * 512);
    }
    if (wid == 2 && lane < 32)                 // 512 B tail
      gld16(src + 41984 + lane * 8, xs + 41984 + lane * 8);
  }

  // ---- as staging: group g = taps p = dh*3 + g (dh 0..2), 128 o ----
  // 48 chunks of 1 KB; wave wid takes chunks wid*6 .. wid*6+5.
  auto stage_a = [&](int g) {
#pragma unroll
    for (int j = 0; j < 6; ++j) {
      const int c = wid * 6 + j;               // 0..47
      const int tap = c >> 4, k = c & 15;      // 16 chunks per tap
      const uint16_t* src =
          Wl + (size_t)(tap * 3 + g) * 32768 + (O0 + k * 8) * 64;
      gld16(src + lane * 8, as + tap * 8192 + k * 512);
    }
  };
  stage_a(0);

  const int wn  = wid;          // h-row within octet
  const int l31 = lane & 31;
  const int hi  = lane >> 5;    // k-half

  float bvv[4];
#pragma unroll
  for (int ob = 0; ob < 4; ++ob)
    bvv[ob] = bias[O0 + ob * 32 + l31];

  f32x16 acc[2][4] = {};        // [pix-sub][o-sub]

  __syncthreads();              // xs + as(group0) resident

#pragma unroll
  for (int g = 0; g < 3; ++g) {
    const int dw = g - 1;
#pragma unroll
    for (int dh = 0; dh < 3; ++dh) {
      const uint16_t* xrow = xs + (wn + dh) * 4224;
#pragma unroll
      for (int q = 0; q < 4; ++q) {            // k-step of 16 (c = q*16..)
        bf16x8 braw[2], af[4];
#pragma unroll
        for (int pb = 0; pb < 2; ++pb) {
          const int wp = pb * 32 + l31 + dw + 1;        // 0..65
          const int slot = (q * 2 + hi) ^ (wp & 7);
          braw[pb] = __builtin_bit_cast(bf16x8,
              *reinterpret_cast<const s16x8*>(xrow + wp * 64 + slot * 8));
        }
#pragma unroll
        for (int ob = 0; ob < 4; ++ob) {
          const int orow = ob * 32 + l31;
          const int slot = (q * 2 + hi) ^ (orow & 7);
          af[ob] = __builtin_bit_cast(bf16x8,
              *reinterpret_cast<const s16x8*>(
                  as + dh * 8192 + orow * 64 + slot * 8));
        }
#pragma unroll
        for (int pb = 0; pb < 2; ++pb)
#pragma unroll
          for (int ob = 0; ob < 4; ++ob)
            acc[pb][ob] = __builtin_amdgcn_mfma_f32_32x32x16_bf16(
                braw[pb], af[ob], acc[pb][ob], 0, 0, 0);
      }
    }
    if (g < 2) {
      __syncthreads();          // all waves done reading as(g)
      stage_a(g + 1);
      __syncthreads();          // as(g+1) resident
    }
  }

  // ---- epilogue: direct f32x4 nt stores ----
  // D (swapped operands, m74 layout): col = o = lane&31,
  // row = pix = (reg&3) + 8*(reg>>2) + 4*(lane>>5) -> reg-quad r4 = 4
  // consecutive w at base pb*32 + r4*8 + hi*4.
  const int h = h0 + wn;
#pragma unroll
  for (int pb = 0; pb < 2; ++pb) {
#pragma unroll
    for (int ob = 0; ob < 4; ++ob) {
      const int o = O0 + ob * 32 + l31;
      const float bv = bvv[ob];
      float* obase = out + ((size_t)(b * NO + o) * NH + h) * NW;
#pragma unroll
      for (int r4 = 0; r4 < 4; ++r4) {
        f32x4 v;
        v[0] = acc[pb][ob][r4 * 4 + 0] + bv;
        v[1] = acc[pb][ob][r4 * 4 + 1] + bv;
        v[2] = acc[pb][ob][r4 * 4 + 2] + bv;
        v[3] = acc[pb][ob][r4 * 4 + 3] + bv;
        const int w = pb * 32 + r4 * 8 + hi * 4;
        __builtin_nontemporal_store(v, reinterpret_cast<f32x4*>(obase + w));
      }
    }
  }
}

extern "C" void kernel_launch(void* const* d_in, const int* in_sizes, int n_in,
                              void* d_out, int out_size, void* d_ws, size_t ws_size,
                              hipStream_t stream) {
  const float* x    = (const float*)d_in[0];
  const float* dict = (const float*)d_in[1];
  const float* coef = (const float*)d_in[2];
  const float* bias = (const float*)d_in[3];
  const int*   idx  = (const int*)d_in[4];
  float* out = (float*)d_out;

  // workspace: xh padded/swizzled = 32*66*66*64*2 B = 17.84 MB at 0;
  //            Wl swizzled 576 KiB at +18 MiB
  uint16_t* xh = (uint16_t*)d_ws;
  uint16_t* Wl = (uint16_t*)((char*)d_ws + (18u << 20));

  hipLaunchKernelGGL(k_prep, dim3(NO + NB * 66), dim3(256), 0, stream,
                     dict, coef, idx, x, Wl, xh);
  hipLaunchKernelGGL(k_conv, dim3(1024), dim3(512), 0, stream,
                     xh, Wl, bias, out);
}

// Round 11
// 116.037 us; speedup vs baseline: 2.3893x; 2.3893x over previous
//
#include <hip/hip_runtime.h>
#include <stdint.h>

// Problem constants (fixed by reference)
#define NB 32    // batch
#define NC 64    // input channels
#define NH 64
#define NW 64
#define NO 512   // output channels
// xh padded layout: [NB][66 hp][66 wp][64 c], hp/wp 0 and 65 are zeros

typedef __bf16 bf16x8 __attribute__((ext_vector_type(8)));
typedef short  s16x8  __attribute__((ext_vector_type(8)));
typedef float  f32x4  __attribute__((ext_vector_type(4)));

__device__ __forceinline__ uint16_t f2bf(float f) {
  uint32_t u = __builtin_bit_cast(uint32_t, f);
  u += 0x7fffu + ((u >> 16) & 1u);   // round-to-nearest-even
  return (uint16_t)(u >> 16);
}

// async global->LDS, 16B per lane. LDS dest = wave-uniform base + lane*16.
__device__ __forceinline__ void gld16(const uint16_t* g, uint16_t* l) {
  __builtin_amdgcn_global_load_lds(
      (const __attribute__((address_space(1))) void*)(g),
      (__attribute__((address_space(3))) void*)(l), 16, 0, 0);
}

// ---------------- kernel 1: fused prep (build_w + nhwc transpose) --------
// bid < NO: W_eff[o][c][p] = sum_s coef[o,s]*dict[idx[o,s]][c][p] ->
//   Wl[((p*NO + o)*8 + ((c>>3) ^ (o&7)))*8 + (c&7)]   (pre-swizzled)
// bid >= NO: x NCHW fp32 -> xh[b][hp][wp][c] bf16, hp/wp-padded (66x66),
//   16B chunk (c>>3) of col wp stored at chunk slot ((c>>3) ^ (wp&7)).
__global__ void k_prep(const float* __restrict__ dict,
                       const float* __restrict__ coef,
                       const int*   __restrict__ idx,
                       const float* __restrict__ x,
                       uint16_t*    __restrict__ Wl,
                       uint16_t*    __restrict__ xh) {
  const int bid = blockIdx.x;
  const int t = threadIdx.x;            // 256
  if (bid < NO) {                       // ---- build_w for o = bid ----
    __shared__ float tmp[576];
    const int o = bid;
#pragma unroll
    for (int j = 0; j < 3; ++j) {
      const int id = t + j * 256;
      if (id < 576) {
        float v = 0.f;
#pragma unroll
        for (int s = 0; s < 4; ++s)
          v += coef[o * 4 + s] * dict[idx[o * 4 + s] * 576 + id];
        tmp[id] = v;
      }
    }
    __syncthreads();
#pragma unroll
    for (int j = 0; j < 3; ++j) {
      const int id = t + j * 256;
      if (id < 576) {
        const int c = id & 63, p = id >> 6;
        const int sl = ((p * NO + o) * 8 + ((c >> 3) ^ (o & 7))) * 8 + (c & 7);
        Wl[sl] = f2bf(tmp[c * 9 + p]);
      }
    }
    return;
  }
  // ---- nhwc for bh = bid - NO ----
  const int bh = bid - NO;              // b*66 + hp
  const int b = bh / 66, hp = bh % 66;
  uint16_t* row = xh + (size_t)(b * 66 + hp) * 4224;   // 66*64 elems
  int4* r4 = reinterpret_cast<int4*>(row);             // 528 int4
  if (hp == 0 || hp == 65) {            // zero h-pad rows
    for (int j = t; j < 528; j += 256) r4[j] = int4{0, 0, 0, 0};
    return;
  }
  __shared__ float tile[64][65];
  const int h = hp - 1;
  const int w = t & 63;
#pragma unroll
  for (int c = (t >> 6); c < 64; c += 4)
    tile[c][w] = x[((size_t)(b * NC + c) * NH + h) * NW + w];
  __syncthreads();
  if (t < 16)                           // zero w-pad cols wp=0 and wp=65
    r4[(t >> 3) * 520 + (t & 7)] = int4{0, 0, 0, 0};
#pragma unroll
  for (int i = 0; i < 2; ++i) {
    const int s = t + i * 256;          // 512 slots: w2 (0..63), cb (0..7)
    const int w2 = s >> 3, cb = s & 7;
    const int wp = w2 + 1;              // padded col
    uint32_t d[4];
#pragma unroll
    for (int j = 0; j < 4; ++j) {
      const uint32_t lo = f2bf(tile[cb * 8 + 2 * j][w2]);
      const uint32_t hi = f2bf(tile[cb * 8 + 2 * j + 1][w2]);
      d[j] = lo | (hi << 16);
    }
    r4[wp * 8 + (cb ^ (wp & 7))] =
        int4{(int)d[0], (int)d[1], (int)d[2], (int)d[3]};
  }
}

// ---------------- kernel 2: 16x16-MFMA conv, reg-double-buffered ---------
// 1024 blocks (4 rounds), 512 thr (8 waves). Block = 128 o x 512 pix
// (8 h-rows of one b). Wave = 64 pix (1 h-row) x 128 o: acc[4][8] f32x4
// (128 VGPR). Per step (g,q,dh): 12 ds_read_b128 -> 32 MFMA (2.67/read;
// LDS floor 34.6us < MFMA floor 37us). Fragments for step s+1 are loaded
// into the OTHER register set before step s's MFMAs (static parity, no
// runtime indexing) so ds_read latency hides under MFMA. No barriers
// inside a 6-step group; as restaged per dw-group (4 coarse barriers).
__global__ __launch_bounds__(512, 2) void k_conv(
    const uint16_t* __restrict__ xh,   // [NB][66][66][64] bf16, pre-swizzled
    const uint16_t* __restrict__ Wl,   // [9][512][64] bf16, pre-swizzled
    const float*    __restrict__ bias,
    float*          __restrict__ out) {
  __shared__ __align__(16) uint16_t xs[10 * 4224];      // 84,480 B
  __shared__ __align__(16) uint16_t as[3 * 128 * 64];   // 49,152 B

  const int t = threadIdx.x;
  const int lane = t & 63;
  const int wid  = t >> 6;      // 0..7
  // XCD-chunked: XCD j gets contiguous range (4 b's, L2-resident)
  const int flat = blockIdx.x;                 // 1024 blocks
  const int sw   = (flat & 7) * 128 + (flat >> 3);
  const int ot   = sw & 3;                     // o-tile (4 x 128)
  const int pt   = sw >> 2;                    // pixel tile: b*8 + h-octet
  const int O0 = ot * 128;
  const int b  = pt >> 3;
  const int h0 = (pt & 7) * 8;

  // ---- stage xs: flat copy of xh rows [b][h0 .. h0+10) (84,480 B) ----
  {
    const uint16_t* src = xh + (size_t)(b * 66 + h0) * 4224;
#pragma unroll
    for (int j = 0; j < 10; ++j) {
      const int ch = wid + j * 8;              // 0..79
      gld16(src + ch * 512 + lane * 8, xs + ch * 512);
    }
    if (wid < 2) {                             // chunks 80, 81
      const int ch = 80 + wid;
      gld16(src + ch * 512 + lane * 8, xs + ch * 512);
    }
    if (wid == 2 && lane < 32)                 // 512 B tail
      gld16(src + 41984 + lane * 8, xs + 41984 + lane * 8);
  }

  // ---- as staging: group g = taps p = dh*3 + g (dh 0..2), 128 o ----
  auto stage_a = [&](int g) {
#pragma unroll
    for (int j = 0; j < 6; ++j) {
      const int c = wid * 6 + j;               // 0..47
      const int tap = c >> 4, k = c & 15;      // 16 chunks per tap
      const uint16_t* src =
          Wl + (size_t)(tap * 3 + g) * 32768 + (O0 + k * 8) * 64;
      gld16(src + lane * 8, as + tap * 8192 + k * 512);
    }
  };
  stage_a(0);

  const int wn  = wid;          // h-row within octet
  const int l15 = lane & 15;
  const int lg  = lane >> 4;    // k-group

  float bvv[8];
#pragma unroll
  for (int ob = 0; ob < 8; ++ob)
    bvv[ob] = bias[O0 + ob * 16 + l15];

  f32x4 acc[4][8] = {};
  bf16x8 fb[2][4], fa[2][8];    // [parity][frag] register double-buffer

#define LOADF(par, gg, ss) do {                                            \
    const int dh_ = (ss) % 3, q_ = (ss) / 3, dw_ = (gg) - 1;               \
    const uint16_t* xrow_ = xs + (wn + dh_) * 4224;                        \
    _Pragma("unroll")                                                      \
    for (int nw = 0; nw < 4; ++nw) {                                       \
      const int wp_ = nw * 16 + l15 + dw_ + 1;                             \
      const int sl_ = (q_ * 4 + lg) ^ (wp_ & 7);                           \
      fb[par][nw] = __builtin_bit_cast(bf16x8,                             \
          *reinterpret_cast<const s16x8*>(xrow_ + wp_ * 64 + sl_ * 8));    \
    }                                                                      \
    const int sa_ = (q_ * 4 + lg) ^ (l15 & 7);                             \
    const uint16_t* ab_ = as + dh_ * 8192 + l15 * 64 + sa_ * 8;            \
    _Pragma("unroll")                                                      \
    for (int ob = 0; ob < 8; ++ob)                                         \
      fa[par][ob] = __builtin_bit_cast(bf16x8,                             \
          *reinterpret_cast<const s16x8*>(ab_ + ob * 1024));               \
  } while (0)

#define MFMASTEP(par) do {                                                 \
    __builtin_amdgcn_s_setprio(1);                                         \
    _Pragma("unroll")                                                      \
    for (int pb = 0; pb < 4; ++pb)                                         \
      _Pragma("unroll")                                                    \
      for (int ob = 0; ob < 8; ++ob)                                       \
        acc[pb][ob] = __builtin_amdgcn_mfma_f32_16x16x32_bf16(             \
            fb[par][pb], fa[par][ob], acc[pb][ob], 0, 0, 0);               \
    __builtin_amdgcn_s_setprio(0);                                         \
  } while (0)

  __syncthreads();              // xs + as(group0) resident

#pragma unroll
  for (int g = 0; g < 3; ++g) {
    LOADF(0, g, 0);
#pragma unroll
    for (int s6 = 0; s6 < 6; ++s6) {
      if (s6 < 5) {
        if ((s6 & 1) == 0) LOADF(1, g, s6 + 1);
        else               LOADF(0, g, s6 + 1);
      }
      if ((s6 & 1) == 0) MFMASTEP(0);
      else               MFMASTEP(1);
    }
    if (g < 2) {
      __syncthreads();          // all waves done reading as(g)
      stage_a(g + 1);
      __syncthreads();          // as(g+1) resident
    }
  }
#undef LOADF
#undef MFMASTEP

  // ---- epilogue: direct f32x4 nt stores (layout verified R7/R8) ----
  const int h = h0 + wn;
#pragma unroll
  for (int pb = 0; pb < 4; ++pb) {
#pragma unroll
    for (int ob = 0; ob < 8; ++ob) {
      const int o = O0 + ob * 16 + l15;
      f32x4 v = acc[pb][ob];
      const float bv = bvv[ob];
      v[0] += bv; v[1] += bv; v[2] += bv; v[3] += bv;
      float* dst = out + ((size_t)(b * NO + o) * NH + h) * NW +
                   pb * 16 + lg * 4;
      __builtin_nontemporal_store(v, reinterpret_cast<f32x4*>(dst));
    }
  }
}

extern "C" void kernel_launch(void* const* d_in, const int* in_sizes, int n_in,
                              void* d_out, int out_size, void* d_ws, size_t ws_size,
                              hipStream_t stream) {
  const float* x    = (const float*)d_in[0];
  const float* dict = (const float*)d_in[1];
  const float* coef = (const float*)d_in[2];
  const float* bias = (const float*)d_in[3];
  const int*   idx  = (const int*)d_in[4];
  float* out = (float*)d_out;

  // workspace: xh padded/swizzled = 32*66*66*64*2 B = 17.84 MB at 0;
  //            Wl swizzled 576 KiB at +18 MiB
  uint16_t* xh = (uint16_t*)d_ws;
  uint16_t* Wl = (uint16_t*)((char*)d_ws + (18u << 20));

  hipLaunchKernelGGL(k_prep, dim3(NO + NB * 66), dim3(256), 0, stream,
                     dict, coef, idx, x, Wl, xh);
  hipLaunchKernelGGL(k_conv, dim3(1024), dim3(512), 0, stream,
                     xh, Wl, bias, out);
}